// Round 21
// baseline (538.524 us; speedup 1.0000x reference)
//
#include <hip/hip_runtime.h>

typedef __attribute__((ext_vector_type(4))) float f32x4;
typedef __attribute__((ext_vector_type(8))) short short8;
typedef __attribute__((ext_vector_type(4))) unsigned short u16x4;

#define MFMA(a,b,c) __builtin_amdgcn_mfma_f32_16x16x32_bf16(a,b,c,0,0,0)

__device__ __forceinline__ unsigned short f2bf(float x){
    union { float f; unsigned int u; } c; c.f = x;
    unsigned int u = c.u;
    unsigned int r = (u + 0x7fffu + ((u >> 16) & 1u)) >> 16;
    return (unsigned short)r;
}
__device__ __forceinline__ unsigned short tf2bf(float x){   // truncating f32->bf16 (1 op)
    union { float f; unsigned int u; } c; c.f = x;
    return (unsigned short)(c.u >> 16);
}
__device__ __forceinline__ float bf2f(unsigned short h){
    union { unsigned int u; float f; } c; c.u = ((unsigned int)h) << 16;
    return c.f;
}

__device__ __forceinline__ void load16_lds(const unsigned short* g, unsigned short* l){
    __builtin_amdgcn_global_load_lds(
        (const __attribute__((address_space(1))) unsigned int*)g,
        (__attribute__((address_space(3))) unsigned int*)l, 16, 0, 0);
}

// XOR-swizzled u16 index, 128B rows (stride 64 u16): byte ^= ((row&7)<<4)
#define SWZ_IDX(row, col, stride) \
    ((row)*(stride) + (((((col) >> 3) ^ ((row) & 7)) << 3) | ((col) & 7)))

// XOR-swizzled u16 index, 64B rows (stride 32 u16, BK=32): slot ^= (row>>1)&3
#define SWZ32(row, col) \
    ((row)*32 + ((((((col) >> 3) ^ (((row) >> 1) & 3))) & 3) << 3) + ((col) & 7))

// ---------------- cast fp32 -> bf16 (vectorized) ----------------
__global__ __launch_bounds__(256) void cast_f32_bf16(const float* __restrict__ in,
                                                     unsigned short* __restrict__ out, int n4){
    int i = blockIdx.x * 256 + threadIdx.x;
    if (i < n4){
        const float4* in4 = (const float4*)in;
        float4 v = in4[i];
        u16x4 o;
        o[0] = f2bf(v.x); o[1] = f2bf(v.y); o[2] = f2bf(v.z); o[3] = f2bf(v.w);
        ((u16x4*)out)[i] = o;
    }
}

// ---------------- GEMM 256x256, 8 waves, BK=32, dbuf 64KB LDS (2 blk/CU), counted vmcnt ----------------
template<int OUT_BF16, int RELU>
__global__ __launch_bounds__(512) void gemm256(const unsigned short* __restrict__ A,
                                               const unsigned short* __restrict__ W,
                                               const float* __restrict__ bias,
                                               void* __restrict__ Cout,
                                               int M, int N, int K)
{
    __shared__ unsigned short Asw[2][256*32];   // 2 x 16KB (swizzled, 64B rows)
    __shared__ unsigned short Bsw[2][256*32];   // 2 x 16KB
    const int tid  = threadIdx.x;
    const int wave = tid >> 6, lane = tid & 63;
    const int wr = wave >> 2, wc = wave & 3;    // 2M x 4N wave grid
    const int lr = lane & 15, lg = lane >> 4;
    const int bm = blockIdx.x, bn = blockIdx.y;

    f32x4 acc[8][4] = {};

    const unsigned short* Ab = A + (size_t)bm*256*K;
    const unsigned short* Wb = W + (size_t)bn*256*K;

    auto stage = [&](int buf, int k0){
        #pragma unroll
        for (int i = 0; i < 2; ++i){
            int c = i*512 + tid;                    // 1024 16B-chunks of the 256x32 tile
            int row = c >> 2, sl = (c & 3) ^ ((row >> 1) & 3);
            load16_lds(Ab + (size_t)row*K + k0 + sl*8, &Asw[buf][0] + (size_t)c*8);
        }
        #pragma unroll
        for (int i = 0; i < 2; ++i){
            int c = i*512 + tid;
            int row = c >> 2, sl = (c & 3) ^ ((row >> 1) & 3);
            load16_lds(Wb + (size_t)row*K + k0 + sl*8, &Bsw[buf][0] + (size_t)c*8);
        }
    };

    stage(0, 0);                      // prologue: tile 0 in flight (4 loads/thread)
    const int NT = K >> 5;
    for (int t = 0; t < NT; ++t){
        const int cur = t & 1;
        if (t + 1 < NT){
            stage(cur ^ 1, (t+1) << 5);                       // issue next tile's 4 loads
            asm volatile("s_waitcnt vmcnt(4)" ::: "memory");  // wait ONLY current tile's 4
        } else {
            asm volatile("s_waitcnt vmcnt(0)" ::: "memory");
        }
        __builtin_amdgcn_s_barrier();        // all waves' tile-t loads published
        asm volatile("" ::: "memory");
        const unsigned short* Al = &Asw[cur][0];
        const unsigned short* Bl = &Bsw[cur][0];
        short8 af[8], bf[4];
        #pragma unroll
        for (int mi = 0; mi < 8; ++mi)
            af[mi] = *(const short8*)(Al + SWZ32(wr*128 + mi*16 + lr, lg*8));
        #pragma unroll
        for (int ni = 0; ni < 4; ++ni)
            bf[ni] = *(const short8*)(Bl + SWZ32(wc*64 + ni*16 + lr, lg*8));
        __builtin_amdgcn_s_setprio(1);
        #pragma unroll
        for (int mi = 0; mi < 8; ++mi)
            #pragma unroll
            for (int ni = 0; ni < 4; ++ni)
                acc[mi][ni] = MFMA(af[mi], bf[ni], acc[mi][ni]);
        __builtin_amdgcn_s_setprio(0);
        asm volatile("" ::: "memory");
        __builtin_amdgcn_s_barrier();        // reads done; next iter may overwrite buf
    }

    #pragma unroll
    for (int ni = 0; ni < 4; ++ni){
        int col = bn*256 + wc*64 + ni*16 + lr;
        float bv = bias ? bias[col] : 0.0f;
        #pragma unroll
        for (int mi = 0; mi < 8; ++mi){
            int row0 = bm*256 + wr*128 + mi*16 + lg*4;
            #pragma unroll
            for (int j = 0; j < 4; ++j){
                float v = acc[mi][ni][j] + bv;
                if (RELU) v = v > 0.0f ? v : 0.0f;
                if (OUT_BF16) ((unsigned short*)Cout)[(size_t)(row0+j)*N + col] = f2bf(v);
                else          ((float*)Cout)[(size_t)(row0+j)*N + col] = v;
            }
        }
    }
}

// ---------------- GEMM 256x128, 8 waves (4Mx2N), BK=32, dbuf 48KB LDS, counted vmcnt ----------------
template<int OUT_BF16, int RELU>
__global__ __launch_bounds__(512) void gemm256x128(const unsigned short* __restrict__ A,
                                                   const unsigned short* __restrict__ W,
                                                   const float* __restrict__ bias,
                                                   void* __restrict__ Cout,
                                                   int M, int N, int K)
{
    __shared__ unsigned short Asw[2][256*32];   // 2 x 16KB (swizzled)
    __shared__ unsigned short Bsw[2][128*32];   // 2 x 8KB
    const int tid  = threadIdx.x;
    const int wave = tid >> 6, lane = tid & 63;
    const int wr = wave >> 1, wc = wave & 1;    // 4M x 2N wave grid
    const int lr = lane & 15, lg = lane >> 4;
    const int bm = blockIdx.x, bn = blockIdx.y;

    f32x4 acc[4][4] = {};

    const unsigned short* Ab = A + (size_t)bm*256*K;
    const unsigned short* Wb = W + (size_t)bn*128*K;

    auto stage = [&](int buf, int k0){
        #pragma unroll
        for (int i = 0; i < 2; ++i){
            int c = i*512 + tid;                    // 1024 chunks: A 256x32
            int row = c >> 2, sl = (c & 3) ^ ((row >> 1) & 3);
            load16_lds(Ab + (size_t)row*K + k0 + sl*8, &Asw[buf][0] + (size_t)c*8);
        }
        {
            int c = tid;                            // 512 chunks: B 128x32
            int row = c >> 2, sl = (c & 3) ^ ((row >> 1) & 3);
            load16_lds(Wb + (size_t)row*K + k0 + sl*8, &Bsw[buf][0] + (size_t)c*8);
        }
    };

    stage(0, 0);                      // prologue (3 loads/thread in flight)
    const int NT = K >> 5;
    for (int t = 0; t < NT; ++t){
        const int cur = t & 1;
        if (t + 1 < NT){
            stage(cur ^ 1, (t+1) << 5);                       // issue next tile's 3 loads
            asm volatile("s_waitcnt vmcnt(3)" ::: "memory");  // wait ONLY current tile's 3
        } else {
            asm volatile("s_waitcnt vmcnt(0)" ::: "memory");
        }
        __builtin_amdgcn_s_barrier();
        asm volatile("" ::: "memory");
        const unsigned short* Al = &Asw[cur][0];
        const unsigned short* Bl = &Bsw[cur][0];
        short8 af[4], bf[4];
        #pragma unroll
        for (int mi = 0; mi < 4; ++mi)
            af[mi] = *(const short8*)(Al + SWZ32(wr*64 + mi*16 + lr, lg*8));
        #pragma unroll
        for (int ni = 0; ni < 4; ++ni)
            bf[ni] = *(const short8*)(Bl + SWZ32(wc*64 + ni*16 + lr, lg*8));
        __builtin_amdgcn_s_setprio(1);
        #pragma unroll
        for (int mi = 0; mi < 4; ++mi)
            #pragma unroll
            for (int ni = 0; ni < 4; ++ni)
                acc[mi][ni] = MFMA(af[mi], bf[ni], acc[mi][ni]);
        __builtin_amdgcn_s_setprio(0);
        asm volatile("" ::: "memory");
        __builtin_amdgcn_s_barrier();
    }

    #pragma unroll
    for (int ni = 0; ni < 4; ++ni){
        int col = bn*128 + wc*64 + ni*16 + lr;
        float bv = bias ? bias[col] : 0.0f;
        #pragma unroll
        for (int mi = 0; mi < 4; ++mi){
            int row0 = bm*256 + wr*64 + mi*16 + lg*4;
            #pragma unroll
            for (int j = 0; j < 4; ++j){
                float v = acc[mi][ni][j] + bv;
                if (RELU) v = v > 0.0f ? v : 0.0f;
                if (OUT_BF16) ((unsigned short*)Cout)[(size_t)(row0+j)*N + col] = f2bf(v);
                else          ((float*)Cout)[(size_t)(row0+j)*N + col] = v;
            }
        }
    }
}

// ---------------- transpose V: qkv[.,2048+h*64+d] -> vt[n][h][d][t] ----------------
__global__ __launch_bounds__(256) void transpose_v(const unsigned short* __restrict__ qkv,
                                                   unsigned short* __restrict__ vt)
{
    __shared__ unsigned short tile[64][80];
    const int tt = blockIdx.x, h = blockIdx.y, n = blockIdx.z;
    const int tid = threadIdx.x;
    #pragma unroll
    for (int i = 0; i < 2; ++i){
        int c = i*256 + tid;
        int row = c >> 3, cc = c & 7;  // t-row, d-chunk
        short8 v = *(const short8*)(qkv + ((size_t)(tt*64+row)*8 + n)*3072 + 2048 + h*64 + cc*8);
        *(short8*)&tile[row][cc*8] = v;
    }
    __syncthreads();
    #pragma unroll
    for (int i = 0; i < 2; ++i){
        int c = i*256 + tid;
        int drow = c >> 3, cc = c & 7;  // d-row, t-chunk
        short8 o;
        #pragma unroll
        for (int j = 0; j < 8; ++j) o[j] = tile[cc*8+j][drow];
        *(short8*)(vt + ((size_t)(n*16+h)*64 + drow)*1024 + tt*64 + cc*8) = o;
    }
}

// ---------------- attention A: 64 q-rows/block, flash-style, dbuf wave-private staging (R18 known-good) ----------------
template<int STORE_P8>
__global__ __launch_bounds__(256) void attn_fused(const unsigned short* __restrict__ qkv,
                                                  const unsigned short* __restrict__ vt,
                                                  float* __restrict__ stats,   // [N][H][S] 1/(16 l)
                                                  unsigned short* __restrict__ ctx,
                                                  unsigned char* __restrict__ p8)
{
    __shared__ unsigned short qs[64*64];        // 8KB Q (swizzled)
    __shared__ unsigned short kt[2][64*64];     // 2x8KB K tiles (swizzled, wave-private rows)
    __shared__ unsigned short vtile[2][64*64];  // 2x8KB Vt tiles (swizzled, wave-private rows)
    __shared__ unsigned short pt[64*64];        // 8KB P tile (swizzled, unnormalized)
    __shared__ float wl[4][64];                 // per-wave partial row sums
    __shared__ float rowinv[64];                // 1/l per row
    const int qb = blockIdx.x, h = blockIdx.y, n = blockIdx.z;
    const int tid = threadIdx.x;
    const int wave = tid >> 6, lane = tid & 63;
    const int lr = lane & 15, lg = lane >> 4;
    const int s0 = qb * 64;
    const float scale = 0.125f;
    const size_t plane = ((size_t)(n*16 + h)) << 20;   // 1MB per (n,h) P8 plane

    // stage Q [64][64] (swizzled ds-write, 2 chunks/thread)
    #pragma unroll
    for (int i = 0; i < 2; ++i){
        int c = i*256 + tid;
        int row = c >> 3, cc = c & 7;
        *(short8*)(qs + SWZ_IDX(row, cc*8, 64)) =
            *(const short8*)(qkv + ((size_t)(s0+row)*8 + n)*3072 + h*64 + cc*8);
    }

    // wave-private staging: wave w stages rows [16w,16w+16) of K-tile and Vt-tile (4 loads/thread)
    auto stageKV = [&](int buf, int tt){
        #pragma unroll
        for (int i = 0; i < 2; ++i){
            int c = wave*128 + i*64 + lane;              // chunks for this wave's 16 rows
            int row = c >> 3, sl = (c & 7) ^ (row & 7);  // inverse-swizzled source slot
            load16_lds(qkv + ((size_t)(tt*64+row)*8 + n)*3072 + 1024 + h*64 + sl*8,
                       &kt[buf][0] + (size_t)c*8);
            load16_lds(vt + ((size_t)(n*16+h)*64 + row)*1024 + tt*64 + sl*8,
                       &vtile[buf][0] + (size_t)c*8);
        }
    };

    stageKV(0, 0);      // prologue
    __syncthreads();    // qs visible to all waves (one-time)

    float lsum[4][4] = {};
    f32x4 av[4] = {};

    for (int tt = 0; tt < 16; ++tt){
        const int cur = tt & 1;
        if (tt + 1 < 16){
            stageKV(cur ^ 1, tt + 1);                         // issue next tile's 4 loads
            asm volatile("s_waitcnt vmcnt(4)" ::: "memory");  // wait ONLY current tile's 4
        } else {
            asm volatile("s_waitcnt vmcnt(0)" ::: "memory");
        }
        asm volatile("" ::: "memory");

        // QK^T: all 64 q-rows vs this wave's 16 K-rows
        f32x4 acc[4] = {};
        #pragma unroll
        for (int kk = 0; kk < 2; ++kk){
            short8 b = *(const short8*)(&kt[cur][0] + SWZ_IDX(wave*16 + lr, kk*32 + lg*8, 64));
            __builtin_amdgcn_s_setprio(1);
            #pragma unroll
            for (int mi = 0; mi < 4; ++mi){
                short8 a = *(const short8*)(qs + SWZ_IDX(mi*16 + lr, kk*32 + lg*8, 64));
                acc[mi] = MFMA(a, b, acc[mi]);
            }
            __builtin_amdgcn_s_setprio(0);
        }
        unsigned short pv16[4][4];
        #pragma unroll
        for (int mi = 0; mi < 4; ++mi)
            #pragma unroll
            for (int j = 0; j < 4; ++j){
                float p = __expf(fminf(acc[mi][j] * scale, 80.0f));
                lsum[mi][j] += p;
                pv16[mi][j] = tf2bf(p);          // truncating pack
            }

        __builtin_amdgcn_s_barrier();   // all waves done PV-reading pt(tt-1)
        asm volatile("" ::: "memory");
        #pragma unroll
        for (int mi = 0; mi < 4; ++mi)
            #pragma unroll
            for (int j = 0; j < 4; ++j)
                pt[SWZ_IDX(mi*16 + lg*4 + j, wave*16 + lr, 64)] = pv16[mi][j];
        asm volatile("" ::: "memory");
        __builtin_amdgcn_s_barrier();   // pt(tt) visible to all waves

        // PV accumulate FIRST: av[q][d] += P[q][t] * Vt[d][t]
        #pragma unroll
        for (int kk = 0; kk < 2; ++kk){
            short8 b = *(const short8*)(&vtile[cur][0] + SWZ_IDX(wave*16 + lr, kk*32 + lg*8, 64));
            __builtin_amdgcn_s_setprio(1);
            #pragma unroll
            for (int mi = 0; mi < 4; ++mi){
                short8 a = *(const short8*)(pt + SWZ_IDX(mi*16 + lr, kk*32 + lg*8, 64));
                av[mi] = MFMA(a, b, av[mi]);
            }
            __builtin_amdgcn_s_setprio(0);
        }

        // P8 export: coalesced pt readback -> u8 quant (q = round(16 p)) -> 8B stores
        if (STORE_P8){
            #pragma unroll
            for (int i = 0; i < 2; ++i){
                int c = i*256 + tid;
                int prow = c >> 3, pcc = c & 7;
                short8 pv = *(const short8*)(pt + SWZ_IDX(prow, pcc*8, 64));
                unsigned int w0 = 0, w1 = 0;
                #pragma unroll
                for (int j = 0; j < 4; ++j){
                    unsigned int q = (unsigned int)fminf(bf2f((unsigned short)pv[j])*16.0f + 0.5f, 255.0f);
                    w0 |= q << (8*j);
                }
                #pragma unroll
                for (int j = 4; j < 8; ++j){
                    unsigned int q = (unsigned int)fminf(bf2f((unsigned short)pv[j])*16.0f + 0.5f, 255.0f);
                    w1 |= q << (8*(j-4));
                }
                uint2* dst = (uint2*)(p8 + plane + (size_t)(s0+prow)*1024 + tt*64 + pcc*8);
                *dst = make_uint2(w0, w1);
            }
        }
    }

    // reduce row sums: over 16 lr lanes, then across waves
    #pragma unroll
    for (int mi = 0; mi < 4; ++mi)
        #pragma unroll
        for (int j = 0; j < 4; ++j){
            float v = lsum[mi][j];
            v += __shfl_xor(v, 1);
            v += __shfl_xor(v, 2);
            v += __shfl_xor(v, 4);
            v += __shfl_xor(v, 8);
            if (lr == 0) wl[wave][mi*16 + lg*4 + j] = v;
        }
    __syncthreads();
    if (tid < 64){
        float l = wl[0][tid] + wl[1][tid] + wl[2][tid] + wl[3][tid];
        float inv = 1.0f / l;
        rowinv[tid] = inv;
        stats[((size_t)(n*16+h)*1024) + s0 + tid] = inv * 0.0625f;
    }
    __syncthreads();

    #pragma unroll
    for (int mi = 0; mi < 4; ++mi)
        #pragma unroll
        for (int j = 0; j < 4; ++j){
            int lrow = mi*16 + lg*4 + j;
            int srow = s0 + lrow;
            int d = wave*16 + lr;
            ctx[((size_t)srow*8 + n)*1024 + h*64 + d] = f2bf(av[mi][j] * rowinv[lrow]);
        }
}

// ---------------- attw from stored P8: out[n][s][t] = sum_h q8 * (stats_h / 16) ----------------
__global__ __launch_bounds__(256) void attw_from_p8(const unsigned char* __restrict__ p8,
                                                    const float* __restrict__ stats,
                                                    float* __restrict__ attw)
{
    __shared__ float c[16];
    const int bid = blockIdx.x;         // n*1024 + s
    const int n = bid >> 10, s = bid & 1023;
    const int tid = threadIdx.x;
    if (tid < 16) c[tid] = stats[(((size_t)(n*16 + tid)) << 10) + s] * (1.0f/16.0f);
    __syncthreads();
    float a0=0.f, a1=0.f, a2=0.f, a3=0.f;
    const unsigned char* base = p8 + ((size_t)n << 24) + ((size_t)s << 10) + tid*4;
    #pragma unroll
    for (int h = 0; h < 16; ++h){
        unsigned int v = *(const unsigned int*)(base + ((size_t)h << 20));
        float ch = c[h];
        a0 += (float)( v         & 255u) * ch;
        a1 += (float)((v >> 8 )  & 255u) * ch;
        a2 += (float)((v >> 16)  & 255u) * ch;
        a3 += (float)( v >> 24         ) * ch;
    }
    float4 o; o.x=a0; o.y=a1; o.z=a2; o.w=a3;
    *(float4*)(attw + ((size_t)bid << 10) + tid*4) = o;
}

// ---------------- attention B (fallback): head-mean recompute, per-wave async pipeline (R14) ----------------
__global__ __launch_bounds__(256) void attn_mean(const unsigned short* __restrict__ qkv,
                                                 const float* __restrict__ stats,
                                                 float* __restrict__ attw)
{
    __shared__ unsigned short qs[16*1024];       // 32KB: 16 q-rows x all 16 heads (swizzled)
    __shared__ unsigned short kv[2][4][16*128];  // 2 buf x 4 waves x 4KB (swizzled, wave-private)
    __shared__ float smL[16][16];                // 1KB: [head][row] 1/(16 l)
    const int qb = blockIdx.x, n = blockIdx.y;
    const int tid = threadIdx.x;
    const int wave = tid >> 6, lane = tid & 63;
    const int lr = lane & 15, lg = lane >> 4;
    const int s0 = qb * 16;
    const float scale = 0.125f;

    {
        int head = tid >> 4, row = tid & 15;
        smL[head][row] = stats[((size_t)(n*16+head)*1024) + s0 + row];
    }
    #pragma unroll
    for (int i = 0; i < 8; ++i){
        int c = i*256 + tid;
        int row = c >> 7, cc = c & 127;
        *(short8*)(qs + SWZ_IDX(row, cc*8, 1024)) =
            *(const short8*)(qkv + ((size_t)(s0+row)*8 + n)*3072 + cc*8);
    }

    unsigned short* kvw = &kv[0][wave][0];
    const int KVBUF = 4*16*128;

    auto stage = [&](int buf, int tt, int g){
        #pragma unroll
        for (int i = 0; i < 4; ++i){
            int c2 = i*64 + lane;
            int rw = c2 >> 4;
            int sd = c2 & 15;
            int sl = sd ^ (rw & 7);
            int trow = tt*64 + wave*16 + rw;
            load16_lds(qkv + ((size_t)trow*8 + n)*3072 + 1024 + g*128 + sl*8,
                       kvw + buf*KVBUF + i*512);
        }
    };

    __syncthreads();
    stage(0, 0, 0);

    float* obase = attw + (size_t)n*1024*1024;
    int r = 0;
    for (int tt = 0; tt < 16; ++tt){
        f32x4 racc = {0.0f, 0.0f, 0.0f, 0.0f};
        for (int g = 0; g < 8; ++g, ++r){
            int nr = r + 1;
            if (nr < 128) stage(nr & 1, nr >> 3, nr & 7);
            if (r < 127) asm volatile("s_waitcnt vmcnt(4)" ::: "memory");
            else         asm volatile("s_waitcnt vmcnt(0)" ::: "memory");
            const unsigned short* kb = kvw + (r & 1)*KVBUF;
            #pragma unroll
            for (int hh = 0; hh < 2; ++hh){
                f32x4 acc = {0.0f, 0.0f, 0.0f, 0.0f};
                #pragma unroll
                for (int kk = 0; kk < 2; ++kk){
                    short8 b = *(const short8*)(kb + SWZ_IDX(lr, hh*64 + kk*32 + lg*8, 128));
                    short8 a = *(const short8*)(qs + SWZ_IDX(lr, g*128 + hh*64 + kk*32 + lg*8, 1024));
                    acc = MFMA(a, b, acc);
                }
                #pragma unroll
                for (int j = 0; j < 4; ++j){
                    float sm = smL[g*2 + hh][lg*4 + j];
                    racc[j] += __expf(fminf(acc[j]*scale, 80.0f)) * sm;
                }
            }
        }
        #pragma unroll
        for (int j = 0; j < 4; ++j)
            obase[(size_t)(s0 + lg*4 + j)*1024 + tt*64 + wave*16 + lr] = racc[j];
    }
}

// ---------------- fused add + LayerNorm ----------------
__global__ __launch_bounds__(256) void add_ln(const float* __restrict__ a,
                                              const float* __restrict__ b,
                                              const float* __restrict__ g,
                                              const float* __restrict__ be,
                                              float* __restrict__ out32,
                                              unsigned short* __restrict__ outbf)
{
    __shared__ float red[8];
    const int row = blockIdx.x;
    const int tid = threadIdx.x;
    const int wave = tid >> 6, lane = tid & 63;
    float4 va = ((const float4*)(a + (size_t)row*1024))[tid];
    float4 vb = ((const float4*)(b + (size_t)row*1024))[tid];
    float x0 = va.x + vb.x, x1 = va.y + vb.y, x2 = va.z + vb.z, x3 = va.w + vb.w;
    float s  = x0 + x1 + x2 + x3;
    float sq = x0*x0 + x1*x1 + x2*x2 + x3*x3;
    #pragma unroll
    for (int off = 1; off < 64; off <<= 1){
        s  += __shfl_xor(s,  off);
        sq += __shfl_xor(sq, off);
    }
    if (lane == 0){ red[wave] = s; red[4+wave] = sq; }
    __syncthreads();
    s  = red[0] + red[1] + red[2] + red[3];
    sq = red[4] + red[5] + red[6] + red[7];
    float mean = s * (1.0f/1024.0f);
    float var  = sq * (1.0f/1024.0f) - mean*mean;
    float rstd = rsqrtf(var + 1e-5f);
    int c = tid * 4;
    float4 vg = ((const float4*)(g  + c))[0];
    float4 vbeta = ((const float4*)(be + c))[0];
    float y0 = (x0-mean)*rstd*vg.x + vbeta.x;
    float y1 = (x1-mean)*rstd*vg.y + vbeta.y;
    float y2 = (x2-mean)*rstd*vg.z + vbeta.z;
    float y3 = (x3-mean)*rstd*vg.w + vbeta.w;
    float4 o; o.x=y0; o.y=y1; o.z=y2; o.w=y3;
    ((float4*)(out32 + (size_t)row*1024))[tid] = o;
    if (outbf){
        u16x4 ob; ob[0]=f2bf(y0); ob[1]=f2bf(y1); ob[2]=f2bf(y2); ob[3]=f2bf(y3);
        ((u16x4*)(outbf + (size_t)row*1024))[tid] = ob;
    }
}

extern "C" void kernel_launch(void* const* d_in, const int* in_sizes, int n_in,
                              void* d_out, int out_size, void* d_ws, size_t ws_size,
                              hipStream_t stream)
{
    (void)in_sizes; (void)n_in; (void)out_size;
    const float* src  = (const float*)d_in[0];
    const float* wqkv = (const float*)d_in[1];
    const float* bqkv = (const float*)d_in[2];
    const float* wout = (const float*)d_in[3];
    const float* bout = (const float*)d_in[4];
    const float* w1   = (const float*)d_in[5];
    const float* b1   = (const float*)d_in[6];
    const float* w2   = (const float*)d_in[7];
    const float* b2   = (const float*)d_in[8];
    const float* g1   = (const float*)d_in[9];
    const float* be1  = (const float*)d_in[10];
    const float* g2   = (const float*)d_in[11];
    const float* be2  = (const float*)d_in[12];

    char* ws = (char*)d_ws;
    const size_t MB = 1ull << 20;
    const bool fastp = (ws_size >= 250*MB);   // deterministic: depends only on ws_size

    unsigned short *wqkv_bf, *wout_bf, *w1_bf, *w2_bf, *src_bf, *x1_bf;
    unsigned short *qkv_bf, *vt_bf, *ff1_bf, *ctx_bf;
    float *attn_out, *ff2_f32, *x1_f32, *stats;
    unsigned char* P8 = nullptr;

    if (fastp){
        // ---- fast layout (249MB): P8 (128MB) alive only attn_fused -> attw_from_p8 ----
        wqkv_bf = (unsigned short*)(ws + 0*MB);
        wout_bf = (unsigned short*)(ws + 6*MB);
        w1_bf   = (unsigned short*)(ws + 8*MB);
        w2_bf   = (unsigned short*)(ws + 16*MB);
        src_bf  = (unsigned short*)(ws + 24*MB);   // dead after QKV gemm
        x1_bf   = (unsigned short*)(ws + 24*MB);   //   alias
        qkv_bf  = (unsigned short*)(ws + 40*MB);   // 48MB, dead after attn
        vt_bf   = (unsigned short*)(ws + 88*MB);   // 16MB, dead after attn
        ff1_bf  = (unsigned short*)(ws + 40*MB);   //   alias qkv+vt (64MB)
        ctx_bf  = (unsigned short*)(ws + 104*MB);  // 16MB
        stats   = (float*)(ws + 120*MB);           // 0.5MB
        P8      = (unsigned char*)(ws + 121*MB);   // 128MB -> end 249MB (dead after attw_from_p8)
        attn_out= (float*)(ws + 121*MB);           //   alias P8[0:32MB] (written after P8 dead)
        ff2_f32 = (float*)(ws + 121*MB);           //   alias attn_out (written after LN1)
        x1_f32  = (float*)(ws + 153*MB);           //   alias P8[32:64MB]
    } else {
        // ---- fallback layout (R14, 184.5MB) ----
        wqkv_bf = (unsigned short*)(ws + 0*MB);
        wout_bf = (unsigned short*)(ws + 6*MB);
        w1_bf   = (unsigned short*)(ws + 8*MB);
        w2_bf   = (unsigned short*)(ws + 16*MB);
        src_bf  = (unsigned short*)(ws + 24*MB);
        x1_bf   = (unsigned short*)(ws + 24*MB);
        qkv_bf  = (unsigned short*)(ws + 40*MB);
        vt_bf   = (unsigned short*)(ws + 88*MB);
        ff1_bf  = (unsigned short*)(ws + 40*MB);
        ctx_bf  = (unsigned short*)(ws + 104*MB);
        attn_out= (float*)(ws + 120*MB);
        ff2_f32 = (float*)(ws + 120*MB);
        x1_f32  = (float*)(ws + 152*MB);
        stats   = (float*)(ws + 184*MB);
    }

    float* x_out    = (float*)d_out;
    float* attw_out = (float*)d_out + (size_t)8192*1024;

    auto cast = [&](const float* in, unsigned short* out, int nelem){
        int n4 = nelem / 4;
        hipLaunchKernelGGL(cast_f32_bf16, dim3((n4 + 255)/256), dim3(256), 0, stream, in, out, n4);
    };
    cast(wqkv, wqkv_bf, 3072*1024);
    cast(wout, wout_bf, 1024*1024);
    cast(w1,   w1_bf,   4096*1024);
    cast(w2,   w2_bf,   1024*4096);
    cast(src,  src_bf,  8192*1024);

    // QKV projection: [8192,3072] (256x128, BK=32, grid 768 = 3 exact CU rounds)
    hipLaunchKernelGGL((gemm256x128<1,0>), dim3(32,24), dim3(512), 0, stream,
                       src_bf, wqkv_bf, bqkv, (void*)qkv_bf, 8192, 3072, 1024);
    // V transpose
    hipLaunchKernelGGL(transpose_v, dim3(16,16,8), dim3(256), 0, stream, qkv_bf, vt_bf);

    if (fastp){
        // attention A: ctx + stats + P8 export (QBLK=64)
        hipLaunchKernelGGL((attn_fused<1>), dim3(16,16,8), dim3(256), 0, stream,
                           qkv_bf, vt_bf, stats, ctx_bf, P8);
        // attw: streaming head-mean from P8
        hipLaunchKernelGGL(attw_from_p8, dim3(8192), dim3(256), 0, stream,
                           P8, stats, attw_out);
    } else {
        hipLaunchKernelGGL((attn_fused<0>), dim3(16,16,8), dim3(256), 0, stream,
                           qkv_bf, vt_bf, stats, ctx_bf, (unsigned char*)nullptr);
        hipLaunchKernelGGL(attn_mean, dim3(64,8), dim3(256), 0, stream,
                           qkv_bf, stats, attw_out);
    }

    // out projection (N=1024: 256x128, BK=32)
    hipLaunchKernelGGL((gemm256x128<0,0>), dim3(32,8), dim3(512), 0, stream,
                       ctx_bf, wout_bf, bout, (void*)attn_out, 8192, 1024, 1024);
    // LN1
    hipLaunchKernelGGL(add_ln, dim3(8192), dim3(256), 0, stream,
                       src, attn_out, g1, be1, x1_f32, x1_bf);
    // FF1 (+bias+relu): [8192,4096] (256^2, BK=32, grid 512 = 2 exact CU rounds)
    hipLaunchKernelGGL((gemm256<1,1>), dim3(32,16), dim3(512), 0, stream,
                       x1_bf, w1_bf, b1, (void*)ff1_bf, 8192, 4096, 1024);
    // FF2 (N=1024: 256x128, BK=32)
    hipLaunchKernelGGL((gemm256x128<0,0>), dim3(32,8), dim3(512), 0, stream,
                       ff1_bf, w2_bf, b2, (void*)ff2_f32, 8192, 1024, 4096);
    // LN2 -> x output
    hipLaunchKernelGGL(add_ln, dim3(8192), dim3(256), 0, stream,
                       x1_f32, ff2_f32, g2, be2, x_out, nullptr);
}

// Round 22
// 517.819 us; speedup vs baseline: 1.0400x; 1.0400x over previous
//
#include <hip/hip_runtime.h>

typedef __attribute__((ext_vector_type(4))) float f32x4;
typedef __attribute__((ext_vector_type(8))) short short8;
typedef __attribute__((ext_vector_type(4))) unsigned short u16x4;

#define MFMA(a,b,c) __builtin_amdgcn_mfma_f32_16x16x32_bf16(a,b,c,0,0,0)

__device__ __forceinline__ unsigned short f2bf(float x){
    union { float f; unsigned int u; } c; c.f = x;
    unsigned int u = c.u;
    unsigned int r = (u + 0x7fffu + ((u >> 16) & 1u)) >> 16;
    return (unsigned short)r;
}
__device__ __forceinline__ unsigned short tf2bf(float x){   // truncating f32->bf16 (1 op)
    union { float f; unsigned int u; } c; c.f = x;
    return (unsigned short)(c.u >> 16);
}
__device__ __forceinline__ float bf2f(unsigned short h){
    union { unsigned int u; float f; } c; c.u = ((unsigned int)h) << 16;
    return c.f;
}

__device__ __forceinline__ void load16_lds(const unsigned short* g, unsigned short* l){
    __builtin_amdgcn_global_load_lds(
        (const __attribute__((address_space(1))) unsigned int*)g,
        (__attribute__((address_space(3))) unsigned int*)l, 16, 0, 0);
}

// XOR-swizzled u16 index into a row-major LDS tile (stride u16 elems, 16B-slot swizzle).
#define SWZ_IDX(row, col, stride) \
    ((row)*(stride) + (((((col) >> 3) ^ ((row) & 7)) << 3) | ((col) & 7)))

// ---------------- cast fp32 -> bf16 (vectorized) ----------------
__global__ __launch_bounds__(256) void cast_f32_bf16(const float* __restrict__ in,
                                                     unsigned short* __restrict__ out, int n4){
    int i = blockIdx.x * 256 + threadIdx.x;
    if (i < n4){
        const float4* in4 = (const float4*)in;
        float4 v = in4[i];
        u16x4 o;
        o[0] = f2bf(v.x); o[1] = f2bf(v.y); o[2] = f2bf(v.z); o[3] = f2bf(v.w);
        ((u16x4*)out)[i] = o;
    }
}

// ---------------- GEMM 256x256, 8 waves, BK=64, dbuf LDS, counted-vmcnt pipeline (R18 known-good) ----------------
template<int OUT_BF16, int RELU>
__global__ __launch_bounds__(512) void gemm256(const unsigned short* __restrict__ A,
                                               const unsigned short* __restrict__ W,
                                               const float* __restrict__ bias,
                                               void* __restrict__ Cout,
                                               int M, int N, int K)
{
    __shared__ unsigned short Asw[2][256*64];   // 2 x 32KB (swizzled)
    __shared__ unsigned short Bsw[2][256*64];   // 2 x 32KB (swizzled)
    const int tid  = threadIdx.x;
    const int wave = tid >> 6, lane = tid & 63;
    const int wr = wave >> 2, wc = wave & 3;    // 2M x 4N wave grid
    const int lr = lane & 15, lg = lane >> 4;
    const int bm = blockIdx.x, bn = blockIdx.y;

    f32x4 acc[8][4] = {};

    const unsigned short* Ab = A + (size_t)bm*256*K;
    const unsigned short* Wb = W + (size_t)bn*256*K;

    auto stage = [&](int buf, int k0){
        #pragma unroll
        for (int i = 0; i < 4; ++i){
            int c = i*512 + tid;                    // 2048 16B-chunks of the 256x64 tile
            int row = c >> 3, sl = (c & 7) ^ (row & 7);   // inverse-swizzled source slot
            load16_lds(Ab + (size_t)row*K + k0 + sl*8, &Asw[buf][0] + (size_t)c*8);
        }
        #pragma unroll
        for (int i = 0; i < 4; ++i){
            int c = i*512 + tid;
            int row = c >> 3, sl = (c & 7) ^ (row & 7);
            load16_lds(Wb + (size_t)row*K + k0 + sl*8, &Bsw[buf][0] + (size_t)c*8);
        }
    };

    stage(0, 0);                      // prologue: tile 0 in flight (8 loads/thread)
    const int NT = K >> 6;
    for (int t = 0; t < NT; ++t){
        const int cur = t & 1;
        if (t + 1 < NT){
            stage(cur ^ 1, (t+1) << 6);                       // issue next tile's 8 loads
            asm volatile("s_waitcnt vmcnt(8)" ::: "memory");  // wait ONLY current tile's 8
        } else {
            asm volatile("s_waitcnt vmcnt(0)" ::: "memory");
        }
        __builtin_amdgcn_s_barrier();        // all waves' tile-t loads published
        asm volatile("" ::: "memory");
        const unsigned short* Al = &Asw[cur][0];
        const unsigned short* Bl = &Bsw[cur][0];
        #pragma unroll
        for (int kk = 0; kk < 2; ++kk){
            short8 af[8], bf[4];
            #pragma unroll
            for (int mi = 0; mi < 8; ++mi)
                af[mi] = *(const short8*)(Al + SWZ_IDX(wr*128 + mi*16 + lr, kk*32 + lg*8, 64));
            #pragma unroll
            for (int ni = 0; ni < 4; ++ni)
                bf[ni] = *(const short8*)(Bl + SWZ_IDX(wc*64 + ni*16 + lr, kk*32 + lg*8, 64));
            __builtin_amdgcn_s_setprio(1);
            #pragma unroll
            for (int mi = 0; mi < 8; ++mi)
                #pragma unroll
                for (int ni = 0; ni < 4; ++ni)
                    acc[mi][ni] = MFMA(af[mi], bf[ni], acc[mi][ni]);
            __builtin_amdgcn_s_setprio(0);
        }
        asm volatile("" ::: "memory");
        __builtin_amdgcn_s_barrier();        // reads done; next iter may overwrite buf
    }

    #pragma unroll
    for (int ni = 0; ni < 4; ++ni){
        int col = bn*256 + wc*64 + ni*16 + lr;
        float bv = bias ? bias[col] : 0.0f;
        #pragma unroll
        for (int mi = 0; mi < 8; ++mi){
            int row0 = bm*256 + wr*128 + mi*16 + lg*4;
            #pragma unroll
            for (int j = 0; j < 4; ++j){
                float v = acc[mi][ni][j] + bv;
                if (RELU) v = v > 0.0f ? v : 0.0f;
                if (OUT_BF16) ((unsigned short*)Cout)[(size_t)(row0+j)*N + col] = f2bf(v);
                else          ((float*)Cout)[(size_t)(row0+j)*N + col] = v;
            }
        }
    }
}

// ---------------- GEMM 256x128, 8 waves (4Mx2N), BK=64, counted-vmcnt pipeline (R13 known-good) ----------------
template<int OUT_BF16, int RELU>
__global__ __launch_bounds__(512) void gemm256x128(const unsigned short* __restrict__ A,
                                                   const unsigned short* __restrict__ W,
                                                   const float* __restrict__ bias,
                                                   void* __restrict__ Cout,
                                                   int M, int N, int K)
{
    __shared__ unsigned short Asw[2][256*64];   // 2 x 32KB (swizzled)
    __shared__ unsigned short Bsw[2][128*64];   // 2 x 16KB (swizzled)
    const int tid  = threadIdx.x;
    const int wave = tid >> 6, lane = tid & 63;
    const int wr = wave >> 1, wc = wave & 1;    // 4M x 2N wave grid
    const int lr = lane & 15, lg = lane >> 4;
    const int bm = blockIdx.x, bn = blockIdx.y;

    f32x4 acc[4][4] = {};

    const unsigned short* Ab = A + (size_t)bm*256*K;
    const unsigned short* Wb = W + (size_t)bn*128*K;

    auto stage = [&](int buf, int k0){
        #pragma unroll
        for (int i = 0; i < 4; ++i){
            int c = i*512 + tid;                    // 2048 chunks: A 256x64
            int row = c >> 3, sl = (c & 7) ^ (row & 7);
            load16_lds(Ab + (size_t)row*K + k0 + sl*8, &Asw[buf][0] + (size_t)c*8);
        }
        #pragma unroll
        for (int i = 0; i < 2; ++i){
            int c = i*512 + tid;                    // 1024 chunks: B 128x64
            int row = c >> 3, sl = (c & 7) ^ (row & 7);
            load16_lds(Wb + (size_t)row*K + k0 + sl*8, &Bsw[buf][0] + (size_t)c*8);
        }
    };

    stage(0, 0);                      // prologue (6 loads/thread in flight)
    const int NT = K >> 6;
    for (int t = 0; t < NT; ++t){
        const int cur = t & 1;
        if (t + 1 < NT){
            stage(cur ^ 1, (t+1) << 6);                       // issue next tile's 6 loads
            asm volatile("s_waitcnt vmcnt(6)" ::: "memory");  // wait ONLY current tile's 6
        } else {
            asm volatile("s_waitcnt vmcnt(0)" ::: "memory");
        }
        __builtin_amdgcn_s_barrier();
        asm volatile("" ::: "memory");
        const unsigned short* Al = &Asw[cur][0];
        const unsigned short* Bl = &Bsw[cur][0];
        #pragma unroll
        for (int kk = 0; kk < 2; ++kk){
            short8 af[4], bf[4];
            #pragma unroll
            for (int mi = 0; mi < 4; ++mi)
                af[mi] = *(const short8*)(Al + SWZ_IDX(wr*64 + mi*16 + lr, kk*32 + lg*8, 64));
            #pragma unroll
            for (int ni = 0; ni < 4; ++ni)
                bf[ni] = *(const short8*)(Bl + SWZ_IDX(wc*64 + ni*16 + lr, kk*32 + lg*8, 64));
            __builtin_amdgcn_s_setprio(1);
            #pragma unroll
            for (int mi = 0; mi < 4; ++mi)
                #pragma unroll
                for (int ni = 0; ni < 4; ++ni)
                    acc[mi][ni] = MFMA(af[mi], bf[ni], acc[mi][ni]);
            __builtin_amdgcn_s_setprio(0);
        }
        asm volatile("" ::: "memory");
        __builtin_amdgcn_s_barrier();
    }

    #pragma unroll
    for (int ni = 0; ni < 4; ++ni){
        int col = bn*128 + wc*64 + ni*16 + lr;
        float bv = bias ? bias[col] : 0.0f;
        #pragma unroll
        for (int mi = 0; mi < 4; ++mi){
            int row0 = bm*256 + wr*64 + mi*16 + lg*4;
            #pragma unroll
            for (int j = 0; j < 4; ++j){
                float v = acc[mi][ni][j] + bv;
                if (RELU) v = v > 0.0f ? v : 0.0f;
                if (OUT_BF16) ((unsigned short*)Cout)[(size_t)(row0+j)*N + col] = f2bf(v);
                else          ((float*)Cout)[(size_t)(row0+j)*N + col] = v;
            }
        }
    }
}

// ---------------- transpose V: qkv[.,2048+h*64+d] -> vt[n][h][d][t] ----------------
__global__ __launch_bounds__(256) void transpose_v(const unsigned short* __restrict__ qkv,
                                                   unsigned short* __restrict__ vt)
{
    __shared__ unsigned short tile[64][80];
    const int tt = blockIdx.x, h = blockIdx.y, n = blockIdx.z;
    const int tid = threadIdx.x;
    #pragma unroll
    for (int i = 0; i < 2; ++i){
        int c = i*256 + tid;
        int row = c >> 3, cc = c & 7;  // t-row, d-chunk
        short8 v = *(const short8*)(qkv + ((size_t)(tt*64+row)*8 + n)*3072 + 2048 + h*64 + cc*8);
        *(short8*)&tile[row][cc*8] = v;
    }
    __syncthreads();
    #pragma unroll
    for (int i = 0; i < 2; ++i){
        int c = i*256 + tid;
        int drow = c >> 3, cc = c & 7;  // d-row, t-chunk
        short8 o;
        #pragma unroll
        for (int j = 0; j < 8; ++j) o[j] = tile[cc*8+j][drow];
        *(short8*)(vt + ((size_t)(n*16+h)*64 + drow)*1024 + tt*64 + cc*8) = o;
    }
}

// ---------------- attention A: 64 q-rows/block, flash-style, dbuf wave-private staging (R18 known-good) ----------------
template<int STORE_P8>
__global__ __launch_bounds__(256) void attn_fused(const unsigned short* __restrict__ qkv,
                                                  const unsigned short* __restrict__ vt,
                                                  float* __restrict__ stats,   // [N][H][S] 1/(16 l)
                                                  unsigned short* __restrict__ ctx,
                                                  unsigned char* __restrict__ p8)
{
    __shared__ unsigned short qs[64*64];        // 8KB Q (swizzled)
    __shared__ unsigned short kt[2][64*64];     // 2x8KB K tiles (swizzled, wave-private rows)
    __shared__ unsigned short vtile[2][64*64];  // 2x8KB Vt tiles (swizzled, wave-private rows)
    __shared__ unsigned short pt[64*64];        // 8KB P tile (swizzled, unnormalized)
    __shared__ float wl[4][64];                 // per-wave partial row sums
    __shared__ float rowinv[64];                // 1/l per row
    const int qb = blockIdx.x, h = blockIdx.y, n = blockIdx.z;
    const int tid = threadIdx.x;
    const int wave = tid >> 6, lane = tid & 63;
    const int lr = lane & 15, lg = lane >> 4;
    const int s0 = qb * 64;
    const float scale = 0.125f;
    const size_t plane = ((size_t)(n*16 + h)) << 20;   // 1MB per (n,h) P8 plane

    // stage Q [64][64] (swizzled ds-write, 2 chunks/thread)
    #pragma unroll
    for (int i = 0; i < 2; ++i){
        int c = i*256 + tid;
        int row = c >> 3, cc = c & 7;
        *(short8*)(qs + SWZ_IDX(row, cc*8, 64)) =
            *(const short8*)(qkv + ((size_t)(s0+row)*8 + n)*3072 + h*64 + cc*8);
    }

    // wave-private staging: wave w stages rows [16w,16w+16) of K-tile and Vt-tile (4 loads/thread)
    auto stageKV = [&](int buf, int tt){
        #pragma unroll
        for (int i = 0; i < 2; ++i){
            int c = wave*128 + i*64 + lane;              // chunks for this wave's 16 rows
            int row = c >> 3, sl = (c & 7) ^ (row & 7);  // inverse-swizzled source slot
            load16_lds(qkv + ((size_t)(tt*64+row)*8 + n)*3072 + 1024 + h*64 + sl*8,
                       &kt[buf][0] + (size_t)c*8);
            load16_lds(vt + ((size_t)(n*16+h)*64 + row)*1024 + tt*64 + sl*8,
                       &vtile[buf][0] + (size_t)c*8);
        }
    };

    stageKV(0, 0);      // prologue
    __syncthreads();    // qs visible to all waves (one-time)

    float lsum[4][4] = {};
    f32x4 av[4] = {};

    for (int tt = 0; tt < 16; ++tt){
        const int cur = tt & 1;
        if (tt + 1 < 16){
            stageKV(cur ^ 1, tt + 1);                         // issue next tile's 4 loads
            asm volatile("s_waitcnt vmcnt(4)" ::: "memory");  // wait ONLY current tile's 4
        } else {
            asm volatile("s_waitcnt vmcnt(0)" ::: "memory");
        }
        asm volatile("" ::: "memory");

        // QK^T: all 64 q-rows vs this wave's 16 K-rows
        f32x4 acc[4] = {};
        #pragma unroll
        for (int kk = 0; kk < 2; ++kk){
            short8 b = *(const short8*)(&kt[cur][0] + SWZ_IDX(wave*16 + lr, kk*32 + lg*8, 64));
            __builtin_amdgcn_s_setprio(1);
            #pragma unroll
            for (int mi = 0; mi < 4; ++mi){
                short8 a = *(const short8*)(qs + SWZ_IDX(mi*16 + lr, kk*32 + lg*8, 64));
                acc[mi] = MFMA(a, b, acc[mi]);
            }
            __builtin_amdgcn_s_setprio(0);
        }
        unsigned short pv16[4][4];
        #pragma unroll
        for (int mi = 0; mi < 4; ++mi)
            #pragma unroll
            for (int j = 0; j < 4; ++j){
                float p = __expf(fminf(acc[mi][j] * scale, 80.0f));
                lsum[mi][j] += p;
                pv16[mi][j] = tf2bf(p);          // truncating pack
            }

        __builtin_amdgcn_s_barrier();   // all waves done PV-reading pt(tt-1)
        asm volatile("" ::: "memory");
        #pragma unroll
        for (int mi = 0; mi < 4; ++mi)
            #pragma unroll
            for (int j = 0; j < 4; ++j)
                pt[SWZ_IDX(mi*16 + lg*4 + j, wave*16 + lr, 64)] = pv16[mi][j];
        asm volatile("" ::: "memory");
        __builtin_amdgcn_s_barrier();   // pt(tt) visible to all waves

        // PV accumulate FIRST: av[q][d] += P[q][t] * Vt[d][t]
        #pragma unroll
        for (int kk = 0; kk < 2; ++kk){
            short8 b = *(const short8*)(&vtile[cur][0] + SWZ_IDX(wave*16 + lr, kk*32 + lg*8, 64));
            __builtin_amdgcn_s_setprio(1);
            #pragma unroll
            for (int mi = 0; mi < 4; ++mi){
                short8 a = *(const short8*)(pt + SWZ_IDX(mi*16 + lr, kk*32 + lg*8, 64));
                av[mi] = MFMA(a, b, av[mi]);
            }
            __builtin_amdgcn_s_setprio(0);
        }

        // P8 export: coalesced pt readback -> u8 quant (q = round(16 p)) -> 8B stores
        if (STORE_P8){
            #pragma unroll
            for (int i = 0; i < 2; ++i){
                int c = i*256 + tid;
                int prow = c >> 3, pcc = c & 7;
                short8 pv = *(const short8*)(pt + SWZ_IDX(prow, pcc*8, 64));
                unsigned int w0 = 0, w1 = 0;
                #pragma unroll
                for (int j = 0; j < 4; ++j){
                    unsigned int q = (unsigned int)fminf(bf2f((unsigned short)pv[j])*16.0f + 0.5f, 255.0f);
                    w0 |= q << (8*j);
                }
                #pragma unroll
                for (int j = 4; j < 8; ++j){
                    unsigned int q = (unsigned int)fminf(bf2f((unsigned short)pv[j])*16.0f + 0.5f, 255.0f);
                    w1 |= q << (8*(j-4));
                }
                uint2* dst = (uint2*)(p8 + plane + (size_t)(s0+prow)*1024 + tt*64 + pcc*8);
                *dst = make_uint2(w0, w1);
            }
        }
    }

    // reduce row sums: over 16 lr lanes, then across waves
    #pragma unroll
    for (int mi = 0; mi < 4; ++mi)
        #pragma unroll
        for (int j = 0; j < 4; ++j){
            float v = lsum[mi][j];
            v += __shfl_xor(v, 1);
            v += __shfl_xor(v, 2);
            v += __shfl_xor(v, 4);
            v += __shfl_xor(v, 8);
            if (lr == 0) wl[wave][mi*16 + lg*4 + j] = v;
        }
    __syncthreads();
    if (tid < 64){
        float l = wl[0][tid] + wl[1][tid] + wl[2][tid] + wl[3][tid];
        float inv = 1.0f / l;
        rowinv[tid] = inv;
        stats[((size_t)(n*16+h)*1024) + s0 + tid] = inv * 0.0625f;
    }
    __syncthreads();

    #pragma unroll
    for (int mi = 0; mi < 4; ++mi)
        #pragma unroll
        for (int j = 0; j < 4; ++j){
            int lrow = mi*16 + lg*4 + j;
            int srow = s0 + lrow;
            int d = wave*16 + lr;
            ctx[((size_t)srow*8 + n)*1024 + h*64 + d] = f2bf(av[mi][j] * rowinv[lrow]);
        }
}

// ---------------- attw from stored P8: out[n][s][t] = sum_h q8 * (stats_h / 16) ----------------
__global__ __launch_bounds__(256) void attw_from_p8(const unsigned char* __restrict__ p8,
                                                    const float* __restrict__ stats,
                                                    float* __restrict__ attw)
{
    __shared__ float c[16];
    const int bid = blockIdx.x;         // n*1024 + s
    const int n = bid >> 10, s = bid & 1023;
    const int tid = threadIdx.x;
    if (tid < 16) c[tid] = stats[(((size_t)(n*16 + tid)) << 10) + s] * (1.0f/16.0f);
    __syncthreads();
    float a0=0.f, a1=0.f, a2=0.f, a3=0.f;
    const unsigned char* base = p8 + ((size_t)n << 24) + ((size_t)s << 10) + tid*4;
    #pragma unroll
    for (int h = 0; h < 16; ++h){
        unsigned int v = *(const unsigned int*)(base + ((size_t)h << 20));
        float ch = c[h];
        a0 += (float)( v         & 255u) * ch;
        a1 += (float)((v >> 8 )  & 255u) * ch;
        a2 += (float)((v >> 16)  & 255u) * ch;
        a3 += (float)( v >> 24         ) * ch;
    }
    float4 o; o.x=a0; o.y=a1; o.z=a2; o.w=a3;
    *(float4*)(attw + ((size_t)bid << 10) + tid*4) = o;
}

// ---------------- attention B (fallback): head-mean recompute, per-wave async pipeline (R14) ----------------
__global__ __launch_bounds__(256) void attn_mean(const unsigned short* __restrict__ qkv,
                                                 const float* __restrict__ stats,
                                                 float* __restrict__ attw)
{
    __shared__ unsigned short qs[16*1024];       // 32KB: 16 q-rows x all 16 heads (swizzled)
    __shared__ unsigned short kv[2][4][16*128];  // 2 buf x 4 waves x 4KB (swizzled, wave-private)
    __shared__ float smL[16][16];                // 1KB: [head][row] 1/(16 l)
    const int qb = blockIdx.x, n = blockIdx.y;
    const int tid = threadIdx.x;
    const int wave = tid >> 6, lane = tid & 63;
    const int lr = lane & 15, lg = lane >> 4;
    const int s0 = qb * 16;
    const float scale = 0.125f;

    {
        int head = tid >> 4, row = tid & 15;
        smL[head][row] = stats[((size_t)(n*16+head)*1024) + s0 + row];
    }
    #pragma unroll
    for (int i = 0; i < 8; ++i){
        int c = i*256 + tid;
        int row = c >> 7, cc = c & 127;
        *(short8*)(qs + SWZ_IDX(row, cc*8, 1024)) =
            *(const short8*)(qkv + ((size_t)(s0+row)*8 + n)*3072 + cc*8);
    }

    unsigned short* kvw = &kv[0][wave][0];
    const int KVBUF = 4*16*128;

    auto stage = [&](int buf, int tt, int g){
        #pragma unroll
        for (int i = 0; i < 4; ++i){
            int c2 = i*64 + lane;
            int rw = c2 >> 4;
            int sd = c2 & 15;
            int sl = sd ^ (rw & 7);
            int trow = tt*64 + wave*16 + rw;
            load16_lds(qkv + ((size_t)trow*8 + n)*3072 + 1024 + g*128 + sl*8,
                       kvw + buf*KVBUF + i*512);
        }
    };

    __syncthreads();
    stage(0, 0, 0);

    float* obase = attw + (size_t)n*1024*1024;
    int r = 0;
    for (int tt = 0; tt < 16; ++tt){
        f32x4 racc = {0.0f, 0.0f, 0.0f, 0.0f};
        for (int g = 0; g < 8; ++g, ++r){
            int nr = r + 1;
            if (nr < 128) stage(nr & 1, nr >> 3, nr & 7);
            if (r < 127) asm volatile("s_waitcnt vmcnt(4)" ::: "memory");
            else         asm volatile("s_waitcnt vmcnt(0)" ::: "memory");
            const unsigned short* kb = kvw + (r & 1)*KVBUF;
            #pragma unroll
            for (int hh = 0; hh < 2; ++hh){
                f32x4 acc = {0.0f, 0.0f, 0.0f, 0.0f};
                #pragma unroll
                for (int kk = 0; kk < 2; ++kk){
                    short8 b = *(const short8*)(kb + SWZ_IDX(lr, hh*64 + kk*32 + lg*8, 128));
                    short8 a = *(const short8*)(qs + SWZ_IDX(lr, g*128 + hh*64 + kk*32 + lg*8, 1024));
                    acc = MFMA(a, b, acc);
                }
                #pragma unroll
                for (int j = 0; j < 4; ++j){
                    float sm = smL[g*2 + hh][lg*4 + j];
                    racc[j] += __expf(fminf(acc[j]*scale, 80.0f)) * sm;
                }
            }
        }
        #pragma unroll
        for (int j = 0; j < 4; ++j)
            obase[(size_t)(s0 + lg*4 + j)*1024 + tt*64 + wave*16 + lr] = racc[j];
    }
}

// ---------------- fused add + LayerNorm ----------------
__global__ __launch_bounds__(256) void add_ln(const float* __restrict__ a,
                                              const float* __restrict__ b,
                                              const float* __restrict__ g,
                                              const float* __restrict__ be,
                                              float* __restrict__ out32,
                                              unsigned short* __restrict__ outbf)
{
    __shared__ float red[8];
    const int row = blockIdx.x;
    const int tid = threadIdx.x;
    const int wave = tid >> 6, lane = tid & 63;
    float4 va = ((const float4*)(a + (size_t)row*1024))[tid];
    float4 vb = ((const float4*)(b + (size_t)row*1024))[tid];
    float x0 = va.x + vb.x, x1 = va.y + vb.y, x2 = va.z + vb.z, x3 = va.w + vb.w;
    float s  = x0 + x1 + x2 + x3;
    float sq = x0*x0 + x1*x1 + x2*x2 + x3*x3;
    #pragma unroll
    for (int off = 1; off < 64; off <<= 1){
        s  += __shfl_xor(s,  off);
        sq += __shfl_xor(sq, off);
    }
    if (lane == 0){ red[wave] = s; red[4+wave] = sq; }
    __syncthreads();
    s  = red[0] + red[1] + red[2] + red[3];
    sq = red[4] + red[5] + red[6] + red[7];
    float mean = s * (1.0f/1024.0f);
    float var  = sq * (1.0f/1024.0f) - mean*mean;
    float rstd = rsqrtf(var + 1e-5f);
    int c = tid * 4;
    float4 vg = ((const float4*)(g  + c))[0];
    float4 vbeta = ((const float4*)(be + c))[0];
    float y0 = (x0-mean)*rstd*vg.x + vbeta.x;
    float y1 = (x1-mean)*rstd*vg.y + vbeta.y;
    float y2 = (x2-mean)*rstd*vg.z + vbeta.z;
    float y3 = (x3-mean)*rstd*vg.w + vbeta.w;
    float4 o; o.x=y0; o.y=y1; o.z=y2; o.w=y3;
    ((float4*)(out32 + (size_t)row*1024))[tid] = o;
    if (outbf){
        u16x4 ob; ob[0]=f2bf(y0); ob[1]=f2bf(y1); ob[2]=f2bf(y2); ob[3]=f2bf(y3);
        ((u16x4*)(outbf + (size_t)row*1024))[tid] = ob;
    }
}

extern "C" void kernel_launch(void* const* d_in, const int* in_sizes, int n_in,
                              void* d_out, int out_size, void* d_ws, size_t ws_size,
                              hipStream_t stream)
{
    (void)in_sizes; (void)n_in; (void)out_size;
    const float* src  = (const float*)d_in[0];
    const float* wqkv = (const float*)d_in[1];
    const float* bqkv = (const float*)d_in[2];
    const float* wout = (const float*)d_in[3];
    const float* bout = (const float*)d_in[4];
    const float* w1   = (const float*)d_in[5];
    const float* b1   = (const float*)d_in[6];
    const float* w2   = (const float*)d_in[7];
    const float* b2   = (const float*)d_in[8];
    const float* g1   = (const float*)d_in[9];
    const float* be1  = (const float*)d_in[10];
    const float* g2   = (const float*)d_in[11];
    const float* be2  = (const float*)d_in[12];

    char* ws = (char*)d_ws;
    const size_t MB = 1ull << 20;
    const bool fastp = (ws_size >= 250*MB);   // deterministic: depends only on ws_size

    unsigned short *wqkv_bf, *wout_bf, *w1_bf, *w2_bf, *src_bf, *x1_bf;
    unsigned short *qkv_bf, *vt_bf, *ff1_bf, *ctx_bf;
    float *attn_out, *ff2_f32, *x1_f32, *stats;
    unsigned char* P8 = nullptr;

    if (fastp){
        // ---- fast layout (249MB): P8 (128MB) alive only attn_fused -> attw_from_p8 ----
        wqkv_bf = (unsigned short*)(ws + 0*MB);
        wout_bf = (unsigned short*)(ws + 6*MB);
        w1_bf   = (unsigned short*)(ws + 8*MB);
        w2_bf   = (unsigned short*)(ws + 16*MB);
        src_bf  = (unsigned short*)(ws + 24*MB);   // dead after QKV gemm
        x1_bf   = (unsigned short*)(ws + 24*MB);   //   alias
        qkv_bf  = (unsigned short*)(ws + 40*MB);   // 48MB, dead after attn
        vt_bf   = (unsigned short*)(ws + 88*MB);   // 16MB, dead after attn
        ff1_bf  = (unsigned short*)(ws + 40*MB);   //   alias qkv+vt (64MB)
        ctx_bf  = (unsigned short*)(ws + 104*MB);  // 16MB
        stats   = (float*)(ws + 120*MB);           // 0.5MB
        P8      = (unsigned char*)(ws + 121*MB);   // 128MB -> end 249MB (dead after attw_from_p8)
        attn_out= (float*)(ws + 121*MB);           //   alias P8[0:32MB] (written after P8 dead)
        ff2_f32 = (float*)(ws + 121*MB);           //   alias attn_out (written after LN1)
        x1_f32  = (float*)(ws + 153*MB);           //   alias P8[32:64MB]
    } else {
        // ---- fallback layout (R14, 184.5MB) ----
        wqkv_bf = (unsigned short*)(ws + 0*MB);
        wout_bf = (unsigned short*)(ws + 6*MB);
        w1_bf   = (unsigned short*)(ws + 8*MB);
        w2_bf   = (unsigned short*)(ws + 16*MB);
        src_bf  = (unsigned short*)(ws + 24*MB);
        x1_bf   = (unsigned short*)(ws + 24*MB);
        qkv_bf  = (unsigned short*)(ws + 40*MB);
        vt_bf   = (unsigned short*)(ws + 88*MB);
        ff1_bf  = (unsigned short*)(ws + 40*MB);
        ctx_bf  = (unsigned short*)(ws + 104*MB);
        attn_out= (float*)(ws + 120*MB);
        ff2_f32 = (float*)(ws + 120*MB);
        x1_f32  = (float*)(ws + 152*MB);
        stats   = (float*)(ws + 184*MB);
    }

    float* x_out    = (float*)d_out;
    float* attw_out = (float*)d_out + (size_t)8192*1024;

    auto cast = [&](const float* in, unsigned short* out, int nelem){
        int n4 = nelem / 4;
        hipLaunchKernelGGL(cast_f32_bf16, dim3((n4 + 255)/256), dim3(256), 0, stream, in, out, n4);
    };
    cast(wqkv, wqkv_bf, 3072*1024);
    cast(wout, wout_bf, 1024*1024);
    cast(w1,   w1_bf,   4096*1024);
    cast(w2,   w2_bf,   1024*4096);
    cast(src,  src_bf,  8192*1024);

    // QKV projection: [8192,3072] (256x128 pipelined, grid 768 = 3 exact CU rounds, no tail)
    hipLaunchKernelGGL((gemm256x128<1,0>), dim3(32,24), dim3(512), 0, stream,
                       src_bf, wqkv_bf, bqkv, (void*)qkv_bf, 8192, 3072, 1024);
    // V transpose
    hipLaunchKernelGGL(transpose_v, dim3(16,16,8), dim3(256), 0, stream, qkv_bf, vt_bf);

    if (fastp){
        // attention A: ctx + stats + P8 export (QBLK=64)
        hipLaunchKernelGGL((attn_fused<1>), dim3(16,16,8), dim3(256), 0, stream,
                           qkv_bf, vt_bf, stats, ctx_bf, P8);
        // attw: streaming head-mean from P8
        hipLaunchKernelGGL(attw_from_p8, dim3(8192), dim3(256), 0, stream,
                           P8, stats, attw_out);
    } else {
        hipLaunchKernelGGL((attn_fused<0>), dim3(16,16,8), dim3(256), 0, stream,
                           qkv_bf, vt_bf, stats, ctx_bf, (unsigned char*)nullptr);
        hipLaunchKernelGGL(attn_mean, dim3(64,8), dim3(256), 0, stream,
                           qkv_bf, stats, attw_out);
    }

    // out projection (N=1024: 256x128 pipelined)
    hipLaunchKernelGGL((gemm256x128<0,0>), dim3(32,8), dim3(512), 0, stream,
                       ctx_bf, wout_bf, bout, (void*)attn_out, 8192, 1024, 1024);
    // LN1
    hipLaunchKernelGGL(add_ln, dim3(8192), dim3(256), 0, stream,
                       src, attn_out, g1, be1, x1_f32, x1_bf);
    // FF1 (+bias+relu): [8192,4096] (256^2 pipelined, grid 512 = 2 exact CU rounds)
    hipLaunchKernelGGL((gemm256<1,1>), dim3(32,16), dim3(512), 0, stream,
                       x1_bf, w1_bf, b1, (void*)ff1_bf, 8192, 4096, 1024);
    // FF2 (N=1024: 256x128 pipelined)
    hipLaunchKernelGGL((gemm256x128<0,0>), dim3(32,8), dim3(512), 0, stream,
                       ff1_bf, w2_bf, b2, (void*)ff2_f32, 8192, 1024, 4096);
    // LN2 -> x output
    hipLaunchKernelGGL(add_ln, dim3(8192), dim3(256), 0, stream,
                       x1_f32, ff2_f32, g2, be2, x_out, nullptr);
}